// Round 7
// baseline (986.679 us; speedup 1.0000x reference)
//
#include <hip/hip_runtime.h>
#include <hip/hip_bf16.h>
#include <stdint.h>

#define NN 8192   // nodes == OUT
#define KIN 512   // input features

typedef __attribute__((ext_vector_type(8))) short bfx8;   // 8 bf16 (4 VGPRs) MFMA operand
typedef __attribute__((ext_vector_type(4))) float f32x4;  // MFMA accumulator
typedef __attribute__((ext_vector_type(4))) short sh4;

__device__ __forceinline__ float b2f(unsigned short u) {
  union { unsigned int i; float f; } z; z.i = ((unsigned int)u) << 16; return z.f;
}
__device__ __forceinline__ unsigned short f2b(float f) {
  __hip_bfloat16 h = __float2bfloat16(f);
  union { __hip_bfloat16 h; unsigned short u; } z; z.h = h; return z.u;
}

// async global->LDS, 16B per lane. LDS dest: wave-uniform base + lane*16.
__device__ __forceinline__ void async16(void* lds, const void* g) {
  __builtin_amdgcn_global_load_lds(
      (const __attribute__((address_space(1))) unsigned int*)g,
      (__attribute__((address_space(3))) unsigned int*)lds,
      16, 0, 0);
}

// fp32 -> bf16 convert (RNE), 4 elems/thread
__global__ __launch_bounds__(256)
void cvt_f32_bf16(const float* __restrict__ in, unsigned short* __restrict__ out, int n4) {
  int i = blockIdx.x * 256 + threadIdx.x;
  if (i >= n4) return;
  const float4 v = reinterpret_cast<const float4*>(in)[i];
  sh4 o;
  o.x = (short)f2b(v.x); o.y = (short)f2b(v.y);
  o.z = (short)f2b(v.z); o.w = (short)f2b(v.w);
  reinterpret_cast<sh4*>(out)[i] = o;
}

// sum 8 fp32 partial planes -> bf16
__global__ __launch_bounds__(256)
void reduce_cvt(const float* __restrict__ P, unsigned short* __restrict__ out, int n4) {
  const int i = blockIdx.x * 256 + threadIdx.x;
  if (i >= n4) return;
  const size_t plane = (size_t)NN * KIN / 4;   // in float4 units
  const float4* P4 = reinterpret_cast<const float4*>(P);
  float4 s = P4[i];
#pragma unroll
  for (int sp = 1; sp < 8; ++sp) {
    const float4 v = P4[i + sp * plane];
    s.x += v.x; s.y += v.y; s.z += v.z; s.w += v.w;
  }
  sh4 o;
  o.x = (short)f2b(s.x); o.y = (short)f2b(s.y);
  o.z = (short)f2b(s.z); o.w = (short)f2b(s.w);
  reinterpret_cast<sh4*>(out)[i] = o;
}

// x (NR x NC f32) -> xT (NC x NR bf16)  AND  xb (NR x NC bf16)
__global__ __launch_bounds__(256)
void transpose_cvt(const float* __restrict__ x, unsigned short* __restrict__ xT,
                   unsigned short* __restrict__ xb, int NR, int NC) {
  __shared__ float t[64][65];
  const int i0 = blockIdx.x << 6;  // row block in x
  const int c0 = blockIdx.y << 6;  // col block in x
  const int tid = threadIdx.x;
  const int rl = tid >> 4;          // 0..15
  const int cl = (tid & 15) << 2;   // 0..60 step 4
#pragma unroll
  for (int ps = 0; ps < 4; ++ps) {
    const int r = rl + (ps << 4);
    const float4 v = *reinterpret_cast<const float4*>(&x[(size_t)(i0 + r) * NC + c0 + cl]);
    t[r][cl] = v.x; t[r][cl + 1] = v.y; t[r][cl + 2] = v.z; t[r][cl + 3] = v.w;
    sh4 o;
    o.x = (short)f2b(v.x); o.y = (short)f2b(v.y);
    o.z = (short)f2b(v.z); o.w = (short)f2b(v.w);
    *reinterpret_cast<sh4*>(&xb[(size_t)(i0 + r) * NC + c0 + cl]) = o;
  }
  __syncthreads();
  const int cr = tid >> 3;          // 0..31
  const int il = (tid & 7) << 3;    // 0..56 step 8
#pragma unroll
  for (int ps = 0; ps < 2; ++ps) {
    const int c = cr + (ps << 5);
    bfx8 o;
#pragma unroll
    for (int j = 0; j < 8; ++j) o[j] = (short)f2b(t[il + j][c]);
    *reinterpret_cast<bfx8*>(&xT[(size_t)(c0 + c) * NR + i0 + il]) = o;
  }
}

// NT GEMM: C[M x Nc] = A[M x K] * B[Nc x K]^T   (both row-major, K contiguous)
// 128x128 tile, BK=32, 4 waves (2x2 of 64x64), 16x16x32 bf16 MFMA.
// MODE 0: C fp32 scaled by rowscale[row].
// MODE 1: C bf16.
// MODE 2: C fp32 partial plane at C + split*M*Nc (split-K, no scale).
// All modes write C through an LDS bounce so global stores are full 128B
// lines (per-fragment scatter = 32/64B segments -> RFO read traffic).
template<int MODE, int SPLITS>
__global__ __launch_bounds__(256)
void gemm_bt(const unsigned short* __restrict__ A,
             const unsigned short* __restrict__ B,
             void* __restrict__ C,
             const float* __restrict__ rowscale,
             int M, int Nc, int K)
{
  __shared__ union {
    struct { unsigned short As[2][128 * 32]; unsigned short Bs[2][128 * 32]; } s; // 32 KiB
    unsigned short ebf[128 * 136];  // bf16 epi tile, pad 136 (272B rows, 16B-mult)
    float          ef[64 * 132];    // fp32 epi half-tile, pad 132 (528B rows)
  } u;

  const int tid  = threadIdx.x;
  const int lane = tid & 63;
  const int wave = tid >> 6;
  const int wr   = wave >> 1, wc = wave & 1;

  // XCD-aware bijective swizzle (gridDim.x % 8 == 0 in all uses here)
  const int nwg = gridDim.x;
  const int cpx = nwg >> 3;
  const int bid = blockIdx.x;
  const int swz = (bid & 7) * cpx + (bid >> 3);
  const int bps = nwg / SPLITS;     // blocks per split
  const int split = swz / bps;
  const int rem   = swz % bps;
  const int nbn = Nc >> 7;
  const int bm  = (rem / nbn) << 7;
  const int bn  = (rem % nbn) << 7;
  const int klen  = K / SPLITS;
  const int kbase = split * klen;

  const int off0 = (wave << 10) + (lane << 4);
  const int r0   = off0 >> 6;
  const int k0e  = (off0 & 63) >> 1;
  const int r1   = r0 + 64;

  const unsigned short* Ag0 = A + (size_t)(bm + r0) * K + kbase + k0e;
  const unsigned short* Ag1 = A + (size_t)(bm + r1) * K + kbase + k0e;
  const unsigned short* Bg0 = B + (size_t)(bn + r0) * K + kbase + k0e;
  const unsigned short* Bg1 = B + (size_t)(bn + r1) * K + kbase + k0e;

  f32x4 acc[4][4];
#pragma unroll
  for (int m = 0; m < 4; ++m)
#pragma unroll
    for (int n = 0; n < 4; ++n)
      acc[m][n] = (f32x4){0.f, 0.f, 0.f, 0.f};

  const int ldsoff = (wave << 10);

  auto stage = [&](int buf, int kk) {
    char* la = (char*)&u.s.As[buf][0] + ldsoff;
    char* lb = (char*)&u.s.Bs[buf][0] + ldsoff;
    async16(la,        Ag0 + kk);
    async16(la + 4096, Ag1 + kk);
    async16(lb,        Bg0 + kk);
    async16(lb + 4096, Bg1 + kk);
  };

  stage(0, 0);
  __syncthreads();

  const int nk   = klen >> 5;
  const int arow = (wr << 6) + (lane & 15);
  const int brow = (wc << 6) + (lane & 15);
  const int koff = (lane >> 4) << 3;

  for (int kt = 0; kt < nk; ++kt) {
    const int cur = kt & 1;
    if (kt + 1 < nk) stage(cur ^ 1, (kt + 1) << 5);

    bfx8 af[4], bf[4];
#pragma unroll
    for (int m = 0; m < 4; ++m)
      af[m] = *reinterpret_cast<const bfx8*>(&u.s.As[cur][(arow + (m << 4)) * 32 + koff]);
#pragma unroll
    for (int n = 0; n < 4; ++n)
      bf[n] = *reinterpret_cast<const bfx8*>(&u.s.Bs[cur][(brow + (n << 4)) * 32 + koff]);

#pragma unroll
    for (int m = 0; m < 4; ++m)
#pragma unroll
      for (int n = 0; n < 4; ++n)
        acc[m][n] = __builtin_amdgcn_mfma_f32_16x16x32_bf16(af[m], bf[n], acc[m][n], 0, 0, 0);

    __syncthreads();  // drains vmcnt: next buffer staged; also guards buffer reuse
  }
  // After the final in-loop barrier every wave is done with LDS staging reads:
  // safe to reuse the union for the epilogue tiles.

  const int l15 = lane & 15;
  const int rq  = (lane >> 4) << 2;   // row quad base within 16-row fragment

  if (MODE == 1) {
    // ---- bf16 tile epilogue: acc -> LDS [128][136] -> 16B/lane stores ----
#pragma unroll
    for (int m = 0; m < 4; ++m)
#pragma unroll
      for (int j = 0; j < 4; ++j) {
        const int lrow = (wr << 6) + (m << 4) + rq + j;
#pragma unroll
        for (int n = 0; n < 4; ++n)
          u.ebf[lrow * 136 + (wc << 6) + (n << 4) + l15] = f2b(acc[m][n][j]);
      }
    __syncthreads();
    unsigned short* Cb = (unsigned short*)C;
#pragma unroll
    for (int it = 0; it < 8; ++it) {
      const int uu = tid + (it << 8);
      const int row = uu >> 4;          // 0..127
      const int ch  = uu & 15;          // 16B chunk
      const bfx8 v = *reinterpret_cast<const bfx8*>(&u.ebf[row * 136 + (ch << 3)]);
      *reinterpret_cast<bfx8*>(&Cb[(size_t)(bm + row) * Nc + bn + (ch << 3)]) = v;
    }
  } else {
    // ---- fp32 epilogue in two 64-row halves: LDS [64][132] -> 16B/lane ----
    float* Cf = (float*)C + (MODE == 2 ? (size_t)split * M * Nc : 0);
#pragma unroll
    for (int h = 0; h < 2; ++h) {
      if (wr == h) {
#pragma unroll
        for (int m = 0; m < 4; ++m)
#pragma unroll
          for (int j = 0; j < 4; ++j) {
            const int lrow = (m << 4) + rq + j;   // 0..63 within half
            float sc = 1.0f;
            if (MODE == 0) sc = rowscale[bm + (h << 6) + lrow];
#pragma unroll
            for (int n = 0; n < 4; ++n)
              u.ef[lrow * 132 + (wc << 6) + (n << 4) + l15] = acc[m][n][j] * sc;
          }
      }
      __syncthreads();
#pragma unroll
      for (int it = 0; it < 8; ++it) {
        const int uu = tid + (it << 8);
        const int row = uu >> 5;          // 0..63
        const int ch  = uu & 31;          // 16B chunk
        const float4 v = *reinterpret_cast<const float4*>(&u.ef[row * 132 + (ch << 2)]);
        *reinterpret_cast<float4*>(&Cf[(size_t)(bm + (h << 6) + row) * Nc + bn + (ch << 2)]) = v;
      }
      __syncthreads();   // half-tile consumed before next half overwrites
    }
  }
}

// row-wise reduce over bf16 matrix. MODE 0: 1/sqrt(sum x^2)  MODE 1: 1/sum
template<int MODE>
__global__ __launch_bounds__(256)
void row_reduce(const unsigned short* __restrict__ X, float* __restrict__ out, int ncols) {
  const int row = blockIdx.x;
  const unsigned short* xr = X + (size_t)row * ncols;
  float s = 0.f;
  for (int c = threadIdx.x * 8; c < ncols; c += 2048) {
    bfx8 v = *reinterpret_cast<const bfx8*>(xr + c);
#pragma unroll
    for (int j = 0; j < 8; ++j) {
      float f = b2f((unsigned short)v[j]);
      s += (MODE == 0) ? f * f : f;
    }
  }
#pragma unroll
  for (int o = 32; o > 0; o >>= 1) s += __shfl_down(s, o);
  __shared__ float red[4];
  if ((threadIdx.x & 63) == 0) red[threadIdx.x >> 6] = s;
  __syncthreads();
  if (threadIdx.x == 0) {
    float t = red[0] + red[1] + red[2] + red[3];
    out[row] = (MODE == 0) ? (1.0f / sqrtf(t)) : (1.0f / t);
  }
}

// in-place 1/x over a small float vector
__global__ __launch_bounds__(256)
void invert_vec(float* __restrict__ v) {
  const int i = blockIdx.x * 256 + threadIdx.x;
  v[i] = 1.0f / v[i];
}

// p[i,j] = adj[i,j] ? exp(lrelu(hT[j,i]*a1[i]*icn[j] + hT[i,j]*a2[j]*icn[i])) : 0
// Vectorized: 8 j per thread. Also accumulates row sums of p into rs_raw[i].
__global__ __launch_bounds__(256)
void scores_kernel(const unsigned short* __restrict__ hT,
                   const int* __restrict__ adj,
                   const float* __restrict__ a,
                   const float* __restrict__ icn,
                   unsigned short* __restrict__ p,
                   float* __restrict__ rs_raw,
                   int strip)
{
  __shared__ unsigned short T1t[64][72];

  const int tid   = threadIdx.x;
  const int i0    = blockIdx.x << 6;
  const int jbase = blockIdx.y * strip;
  const int ntile = strip >> 6;

  const int slot = tid & 7;
  const int jb   = slot << 3;
  const int il0  = tid >> 3;
  const int i_p0 = i0 + il0;
  const int i_p1 = i_p0 + 32;
  const float a1_0 = a[i_p0], ici_0 = icn[i_p0];
  const float a1_1 = a[i_p1], ici_1 = icn[i_p1];
  float rs0 = 0.f, rs1 = 0.f;

  const int rblk0 = (((jb >> 3) ^ ((il0 >> 3) & 7)) << 3);
  const int rblk1 = (((jb >> 3) ^ (((il0 + 32) >> 3) & 7)) << 3);

  for (int jt = 0; jt < ntile; ++jt) {
    const int j0 = jbase + (jt << 6);
    __syncthreads();
#pragma unroll
    for (int ss = 0; ss < 2; ++ss) {
      const int uu = tid + (ss << 8);
      const int jr = uu >> 3;
      const int cb = (uu & 7) << 3;
      const bfx8 v = *reinterpret_cast<const bfx8*>(hT + (size_t)(j0 + jr) * NN + i0 + cb);
      const int colp = ((((jr >> 3) ^ (uu & 7)) << 3) | (jr & 7));
#pragma unroll
      for (int k = 0; k < 8; ++k) T1t[cb + k][colp] = (unsigned short)v[k];
    }
    __syncthreads();

    const int j = j0 + jb;
    const float4 ic0 = *reinterpret_cast<const float4*>(icn + j);
    const float4 ic1 = *reinterpret_cast<const float4*>(icn + j + 4);
    const float4 a20 = *reinterpret_cast<const float4*>(a + NN + j);
    const float4 a21 = *reinterpret_cast<const float4*>(a + NN + j + 4);
    const float icj[8] = {ic0.x, ic0.y, ic0.z, ic0.w, ic1.x, ic1.y, ic1.z, ic1.w};
    const float a2j[8] = {a20.x, a20.y, a20.z, a20.w, a21.x, a21.y, a21.z, a21.w};

#pragma unroll
    for (int ps = 0; ps < 2; ++ps) {
      const int il   = (ps == 0) ? il0 : il0 + 32;
      const int i    = (ps == 0) ? i_p0 : i_p1;
      const float a1 = (ps == 0) ? a1_0 : a1_1;
      const float ii = (ps == 0) ? ici_0 : ici_1;
      const int rb   = (ps == 0) ? rblk0 : rblk1;

      const bfx8 hijv = *reinterpret_cast<const bfx8*>(&T1t[il][rb]);
      const bfx8 hjiv = *reinterpret_cast<const bfx8*>(hT + (size_t)i * NN + j);
      const int4 ad0  = *reinterpret_cast<const int4*>(adj + (size_t)i * NN + j);
      const int4 ad1  = *reinterpret_cast<const int4*>(adj + (size_t)i * NN + j + 4);
      const int adv[8] = {ad0.x, ad0.y, ad0.z, ad0.w, ad1.x, ad1.y, ad1.z, ad1.w};

      bfx8 o;
      float rs = 0.f;
#pragma unroll
      for (int k = 0; k < 8; ++k) {
        const float hij = b2f((unsigned short)hijv[k]);
        const float hji = b2f((unsigned short)hjiv[k]);
        const float e0  = hij * (a1 * icj[k]) + hji * (a2j[k] * ii);
        const float e   = e0 > 0.f ? e0 : 0.2f * e0;
        const float pv  = (adv[k] > 0) ? __expf(e) : 0.f;
        const unsigned short ub = f2b(pv);
        o[k] = (short)ub;
        rs += b2f(ub);
      }
      *reinterpret_cast<bfx8*>(p + (size_t)i * NN + j) = o;
      if (ps == 0) rs0 += rs; else rs1 += rs;
    }
  }

#pragma unroll
  for (int o = 1; o < 8; o <<= 1) {
    rs0 += __shfl_xor(rs0, o);
    rs1 += __shfl_xor(rs1, o);
  }
  if (slot == 0) {
    atomicAdd(rs_raw + i_p0, rs0);
    atomicAdd(rs_raw + i_p1, rs1);
  }
}

extern "C" void kernel_launch(void* const* d_in, const int* in_sizes, int n_in,
                              void* d_out, int out_size, void* d_ws, size_t ws_size,
                              hipStream_t stream)
{
  (void)in_sizes; (void)n_in; (void)out_size; (void)ws_size;
  const float* x   = (const float*)d_in[0];
  const int*   adj = (const int*)d_in[1];
  const float* W   = (const float*)d_in[2];
  const float* a   = (const float*)d_in[3];
  float* out = (float*)d_out;

  char* ws = (char*)d_ws;
  // layout (no recycling; ~289 MiB used, ws ~1 GiB):
  //   hT 128MiB | p 128MiB | icn 32KiB | irs 32KiB | xb 8MiB | Wb 8MiB | xT 8MiB | Axb 8MiB
  // split-K partials (8 x 16MiB fp32) live in d_out, dead before gemm2b writes it.
  unsigned short* hT = (unsigned short*)ws;
  unsigned short* p  = (unsigned short*)(ws + 134217728ull);
  float* icn = (float*)(ws + 268435456ull);
  float* irs = (float*)(ws + 268435456ull + 32768ull);
  unsigned short* xb  = (unsigned short*)(ws + 268435456ull + 65536ull);
  unsigned short* Wb  = xb + (size_t)NN * KIN;
  unsigned short* xT  = Wb + (size_t)NN * KIN;
  unsigned short* Axb = xT + (size_t)NN * KIN;
  float* parts = out;

  // irs doubles as the raw row-sum accumulator for scores' atomics
  hipMemsetAsync(irs, 0, NN * sizeof(float), stream);

  const int n4 = NN * KIN / 4;
  // xb + xT from one read of x
  transpose_cvt<<<dim3(NN / 64, KIN / 64), 256, 0, stream>>>(x, xT, xb, NN, KIN);
  cvt_f32_bf16<<<n4 / 256, 256, 0, stream>>>(W, Wb, n4);

  // hT[j,i] = sum_k W[j,k] x[i,k]
  gemm_bt<1, 1><<<4096, 256, 0, stream>>>(Wb, xb, hT, nullptr, NN, NN, KIN);

  // icn[j] = 1 / ||hT[j,:]||
  row_reduce<0><<<NN, 256, 0, stream>>>(hT, icn, NN);

  // p[i,j] = adj ? exp(lrelu(...)) : 0 ; rowsums -> irs (raw)
  scores_kernel<<<dim3(128, 16), 256, 0, stream>>>(hT, adj, a, icn, p, irs, NN / 16);

  // irs[i] = 1 / rowsum[i]
  invert_vec<<<NN / 256, 256, 0, stream>>>(irs);

  // Ax[i,c] = sum_j p[i,j] * x[j,c]  (split-K 8, partials in d_out)
  gemm_bt<2, 8><<<2048, 256, 0, stream>>>(p, xT, parts, nullptr, NN, KIN, NN);

  // Axb = bf16(sum of 8 partial planes)
  reduce_cvt<<<n4 / 256, 256, 0, stream>>>(parts, Axb, n4);

  // out[i,j] = (sum_c Ax[i,c] * W[j,c]) * irs[i]
  gemm_bt<0, 1><<<4096, 256, 0, stream>>>(Axb, Wb, out, irs, NN, NN, KIN);
}

// Round 8
// 543.981 us; speedup vs baseline: 1.8138x; 1.8138x over previous
//
#include <hip/hip_runtime.h>
#include <hip/hip_bf16.h>
#include <stdint.h>

#define NN 8192   // nodes == OUT
#define KIN 512   // input features

typedef __attribute__((ext_vector_type(8))) short bfx8;   // 8 bf16 (4 VGPRs) MFMA operand
typedef __attribute__((ext_vector_type(4))) float f32x4;  // MFMA accumulator
typedef __attribute__((ext_vector_type(4))) short sh4;

__device__ __forceinline__ float b2f(unsigned short u) {
  union { unsigned int i; float f; } z; z.i = ((unsigned int)u) << 16; return z.f;
}
__device__ __forceinline__ unsigned short f2b(float f) {
  __hip_bfloat16 h = __float2bfloat16(f);
  union { __hip_bfloat16 h; unsigned short u; } z; z.h = h; return z.u;
}

// async global->LDS, 16B per lane. LDS dest: wave-uniform base + lane*16.
__device__ __forceinline__ void async16(void* lds, const void* g) {
  __builtin_amdgcn_global_load_lds(
      (const __attribute__((address_space(1))) unsigned int*)g,
      (__attribute__((address_space(3))) unsigned int*)lds,
      16, 0, 0);
}

// fp32 -> bf16 convert (RNE), 4 elems/thread
__global__ __launch_bounds__(256)
void cvt_f32_bf16(const float* __restrict__ in, unsigned short* __restrict__ out, int n4) {
  int i = blockIdx.x * 256 + threadIdx.x;
  if (i >= n4) return;
  const float4 v = reinterpret_cast<const float4*>(in)[i];
  sh4 o;
  o.x = (short)f2b(v.x); o.y = (short)f2b(v.y);
  o.z = (short)f2b(v.z); o.w = (short)f2b(v.w);
  reinterpret_cast<sh4*>(out)[i] = o;
}

// sum 8 fp32 partial planes -> bf16
__global__ __launch_bounds__(256)
void reduce_cvt(const float* __restrict__ P, unsigned short* __restrict__ out, int n4) {
  const int i = blockIdx.x * 256 + threadIdx.x;
  if (i >= n4) return;
  const size_t plane = (size_t)NN * KIN / 4;   // in float4 units
  const float4* P4 = reinterpret_cast<const float4*>(P);
  float4 s = P4[i];
#pragma unroll
  for (int sp = 1; sp < 8; ++sp) {
    const float4 v = P4[i + sp * plane];
    s.x += v.x; s.y += v.y; s.z += v.z; s.w += v.w;
  }
  sh4 o;
  o.x = (short)f2b(s.x); o.y = (short)f2b(s.y);
  o.z = (short)f2b(s.z); o.w = (short)f2b(s.w);
  reinterpret_cast<sh4*>(out)[i] = o;
}

// x (NR x NC f32, row-major) -> xT (NC x NR bf16, row-major)
__global__ __launch_bounds__(256)
void transpose_cvt(const float* __restrict__ x, unsigned short* __restrict__ xT,
                   int NR, int NC) {
  __shared__ float t[64][65];
  const int i0 = blockIdx.x << 6;  // row block in x
  const int c0 = blockIdx.y << 6;  // col block in x
  const int tid = threadIdx.x;
  const int rl = tid >> 4;          // 0..15
  const int cl = (tid & 15) << 2;   // 0..60 step 4
#pragma unroll
  for (int ps = 0; ps < 4; ++ps) {
    const int r = rl + (ps << 4);
    const float4 v = *reinterpret_cast<const float4*>(&x[(size_t)(i0 + r) * NC + c0 + cl]);
    t[r][cl] = v.x; t[r][cl + 1] = v.y; t[r][cl + 2] = v.z; t[r][cl + 3] = v.w;
  }
  __syncthreads();
  const int cr = tid >> 3;          // 0..31
  const int il = (tid & 7) << 3;    // 0..56 step 8
#pragma unroll
  for (int ps = 0; ps < 2; ++ps) {
    const int c = cr + (ps << 5);
    bfx8 o;
#pragma unroll
    for (int j = 0; j < 8; ++j) o[j] = (short)f2b(t[il + j][c]);
    *reinterpret_cast<bfx8*>(&xT[(size_t)(c0 + c) * NR + i0 + il]) = o;
  }
}

// NT GEMM: C[M x Nc] = A[M x K] * B[Nc x K]^T   (both row-major, K contiguous)
// 128x128 tile, BK=32, 4 waves (2x2 of 64x64), 16x16x32 bf16 MFMA.
// MODE 0: C fp32, scaled by rowscale[row], nontemporal (out: never re-read).
// MODE 1: C bf16, nontemporal (hT: re-read only by later kernels via HBM/L3).
// MODE 2: C fp32 partial plane at C + split*M*Nc (split-K; normal stores,
//         re-read immediately by reduce_cvt so L3 residency is valuable).
template<int MODE, int SPLITS>
__global__ __launch_bounds__(256)
void gemm_bt(const unsigned short* __restrict__ A,
             const unsigned short* __restrict__ B,
             void* __restrict__ C,
             const float* __restrict__ rowscale,
             int M, int Nc, int K)
{
  __shared__ unsigned short As[2][128 * 32];
  __shared__ unsigned short Bs[2][128 * 32];

  const int tid  = threadIdx.x;
  const int lane = tid & 63;
  const int wave = tid >> 6;
  const int wr   = wave >> 1, wc = wave & 1;

  // XCD-aware bijective swizzle (gridDim.x % 8 == 0 in all uses here)
  const int nwg = gridDim.x;
  const int cpx = nwg >> 3;
  const int bid = blockIdx.x;
  const int swz = (bid & 7) * cpx + (bid >> 3);
  const int bps = nwg / SPLITS;     // blocks per split
  const int split = swz / bps;
  const int rem   = swz % bps;
  const int nbn = Nc >> 7;
  const int bm  = (rem / nbn) << 7;
  const int bn  = (rem % nbn) << 7;
  const int klen  = K / SPLITS;
  const int kbase = split * klen;

  const int off0 = (wave << 10) + (lane << 4);
  const int r0   = off0 >> 6;
  const int k0e  = (off0 & 63) >> 1;
  const int r1   = r0 + 64;

  const unsigned short* Ag0 = A + (size_t)(bm + r0) * K + kbase + k0e;
  const unsigned short* Ag1 = A + (size_t)(bm + r1) * K + kbase + k0e;
  const unsigned short* Bg0 = B + (size_t)(bn + r0) * K + kbase + k0e;
  const unsigned short* Bg1 = B + (size_t)(bn + r1) * K + kbase + k0e;

  f32x4 acc[4][4];
#pragma unroll
  for (int m = 0; m < 4; ++m)
#pragma unroll
    for (int n = 0; n < 4; ++n)
      acc[m][n] = (f32x4){0.f, 0.f, 0.f, 0.f};

  const int ldsoff = (wave << 10);

  auto stage = [&](int buf, int kk) {
    char* la = (char*)&As[buf][0] + ldsoff;
    char* lb = (char*)&Bs[buf][0] + ldsoff;
    async16(la,        Ag0 + kk);
    async16(la + 4096, Ag1 + kk);
    async16(lb,        Bg0 + kk);
    async16(lb + 4096, Bg1 + kk);
  };

  stage(0, 0);
  __syncthreads();

  const int nk   = klen >> 5;
  const int arow = (wr << 6) + (lane & 15);
  const int brow = (wc << 6) + (lane & 15);
  const int koff = (lane >> 4) << 3;

  for (int kt = 0; kt < nk; ++kt) {
    const int cur = kt & 1;
    if (kt + 1 < nk) stage(cur ^ 1, (kt + 1) << 5);

    bfx8 af[4], bf[4];
#pragma unroll
    for (int m = 0; m < 4; ++m)
      af[m] = *reinterpret_cast<const bfx8*>(&As[cur][(arow + (m << 4)) * 32 + koff]);
#pragma unroll
    for (int n = 0; n < 4; ++n)
      bf[n] = *reinterpret_cast<const bfx8*>(&Bs[cur][(brow + (n << 4)) * 32 + koff]);

#pragma unroll
    for (int m = 0; m < 4; ++m)
#pragma unroll
      for (int n = 0; n < 4; ++n)
        acc[m][n] = __builtin_amdgcn_mfma_f32_16x16x32_bf16(af[m], bf[n], acc[m][n], 0, 0, 0);

    __syncthreads();  // drains vmcnt: next buffer staged; also guards buffer reuse
  }

  // C/D layout: col = lane&15, row = (lane>>4)*4 + reg
#pragma unroll
  for (int m = 0; m < 4; ++m) {
    const int rowb = bm + (wr << 6) + (m << 4) + ((lane >> 4) << 2);
#pragma unroll
    for (int j = 0; j < 4; ++j) {
      const int r = rowb + j;
      if (MODE == 1) {
        unsigned short* Cb = (unsigned short*)C;
#pragma unroll
        for (int n = 0; n < 4; ++n)
          __builtin_nontemporal_store(f2b(acc[m][n][j]),
              &Cb[(size_t)r * Nc + bn + (wc << 6) + (n << 4) + (lane & 15)]);
      } else if (MODE == 0) {
        const float s = rowscale[r];
        float* Cf = (float*)C;
#pragma unroll
        for (int n = 0; n < 4; ++n)
          __builtin_nontemporal_store(acc[m][n][j] * s,
              &Cf[(size_t)r * Nc + bn + (wc << 6) + (n << 4) + (lane & 15)]);
      } else {
        float* Cf = (float*)C + (size_t)split * M * Nc;
#pragma unroll
        for (int n = 0; n < 4; ++n)
          Cf[(size_t)r * Nc + bn + (wc << 6) + (n << 4) + (lane & 15)] = acc[m][n][j];
      }
    }
  }
}

// row-wise reduce over bf16 matrix. MODE 0: 1/sqrt(sum x^2)  MODE 1: 1/sum
template<int MODE>
__global__ __launch_bounds__(256)
void row_reduce(const unsigned short* __restrict__ X, float* __restrict__ out, int ncols) {
  const int row = blockIdx.x;
  const unsigned short* xr = X + (size_t)row * ncols;
  float s = 0.f;
  for (int c = threadIdx.x * 8; c < ncols; c += 2048) {
    bfx8 v = *reinterpret_cast<const bfx8*>(xr + c);
#pragma unroll
    for (int j = 0; j < 8; ++j) {
      float f = b2f((unsigned short)v[j]);
      s += (MODE == 0) ? f * f : f;
    }
  }
#pragma unroll
  for (int o = 32; o > 0; o >>= 1) s += __shfl_down(s, o);
  __shared__ float red[4];
  if ((threadIdx.x & 63) == 0) red[threadIdx.x >> 6] = s;
  __syncthreads();
  if (threadIdx.x == 0) {
    float t = red[0] + red[1] + red[2] + red[3];
    out[row] = (MODE == 0) ? (1.0f / sqrtf(t)) : (1.0f / t);
  }
}

// in-place 1/x over a small float vector
__global__ __launch_bounds__(256)
void invert_vec(float* __restrict__ v) {
  const int i = blockIdx.x * 256 + threadIdx.x;
  v[i] = 1.0f / v[i];
}

// p[i,j] = adj[i,j] ? exp(lrelu(hT[j,i]*a1[i]*icn[j] + hT[i,j]*a2[j]*icn[i])) : 0
// Vectorized: 8 j per thread. Also accumulates row sums of p into rs_raw[i].
__global__ __launch_bounds__(256)
void scores_kernel(const unsigned short* __restrict__ hT,
                   const int* __restrict__ adj,
                   const float* __restrict__ a,
                   const float* __restrict__ icn,
                   unsigned short* __restrict__ p,
                   float* __restrict__ rs_raw,
                   int strip)
{
  __shared__ unsigned short T1t[64][72];

  const int tid   = threadIdx.x;
  const int i0    = blockIdx.x << 6;
  const int jbase = blockIdx.y * strip;
  const int ntile = strip >> 6;

  const int slot = tid & 7;
  const int jb   = slot << 3;
  const int il0  = tid >> 3;
  const int i_p0 = i0 + il0;
  const int i_p1 = i_p0 + 32;
  const float a1_0 = a[i_p0], ici_0 = icn[i_p0];
  const float a1_1 = a[i_p1], ici_1 = icn[i_p1];
  float rs0 = 0.f, rs1 = 0.f;

  const int rblk0 = (((jb >> 3) ^ ((il0 >> 3) & 7)) << 3);
  const int rblk1 = (((jb >> 3) ^ (((il0 + 32) >> 3) & 7)) << 3);

  for (int jt = 0; jt < ntile; ++jt) {
    const int j0 = jbase + (jt << 6);
    __syncthreads();
#pragma unroll
    for (int ss = 0; ss < 2; ++ss) {
      const int u  = tid + (ss << 8);
      const int jr = u >> 3;
      const int cb = (u & 7) << 3;
      const bfx8 v = *reinterpret_cast<const bfx8*>(hT + (size_t)(j0 + jr) * NN + i0 + cb);
      const int colp = ((((jr >> 3) ^ (u & 7)) << 3) | (jr & 7));
#pragma unroll
      for (int k = 0; k < 8; ++k) T1t[cb + k][colp] = (unsigned short)v[k];
    }
    __syncthreads();

    const int j = j0 + jb;
    const float4 ic0 = *reinterpret_cast<const float4*>(icn + j);
    const float4 ic1 = *reinterpret_cast<const float4*>(icn + j + 4);
    const float4 a20 = *reinterpret_cast<const float4*>(a + NN + j);
    const float4 a21 = *reinterpret_cast<const float4*>(a + NN + j + 4);
    const float icj[8] = {ic0.x, ic0.y, ic0.z, ic0.w, ic1.x, ic1.y, ic1.z, ic1.w};
    const float a2j[8] = {a20.x, a20.y, a20.z, a20.w, a21.x, a21.y, a21.z, a21.w};

#pragma unroll
    for (int ps = 0; ps < 2; ++ps) {
      const int il   = (ps == 0) ? il0 : il0 + 32;
      const int i    = (ps == 0) ? i_p0 : i_p1;
      const float a1 = (ps == 0) ? a1_0 : a1_1;
      const float ii = (ps == 0) ? ici_0 : ici_1;
      const int rb   = (ps == 0) ? rblk0 : rblk1;

      const bfx8 hijv = *reinterpret_cast<const bfx8*>(&T1t[il][rb]);
      const bfx8 hjiv = *reinterpret_cast<const bfx8*>(hT + (size_t)i * NN + j);
      const int4 ad0  = *reinterpret_cast<const int4*>(adj + (size_t)i * NN + j);
      const int4 ad1  = *reinterpret_cast<const int4*>(adj + (size_t)i * NN + j + 4);
      const int adv[8] = {ad0.x, ad0.y, ad0.z, ad0.w, ad1.x, ad1.y, ad1.z, ad1.w};

      bfx8 o;
      float rs = 0.f;
#pragma unroll
      for (int k = 0; k < 8; ++k) {
        const float hij = b2f((unsigned short)hijv[k]);
        const float hji = b2f((unsigned short)hjiv[k]);
        const float e0  = hij * (a1 * icj[k]) + hji * (a2j[k] * ii);
        const float e   = e0 > 0.f ? e0 : 0.2f * e0;
        const float pv  = (adv[k] > 0) ? __expf(e) : 0.f;
        const unsigned short ub = f2b(pv);
        o[k] = (short)ub;
        rs += b2f(ub);   // accumulate the rounded value (matches reading back bf16 p)
      }
      *reinterpret_cast<bfx8*>(p + (size_t)i * NN + j) = o;
      if (ps == 0) rs0 += rs; else rs1 += rs;
    }
  }

  // reduce across the 8 j-slot lanes (lane groups are 8-aligned)
#pragma unroll
  for (int o = 1; o < 8; o <<= 1) {
    rs0 += __shfl_xor(rs0, o);
    rs1 += __shfl_xor(rs1, o);
  }
  if (slot == 0) {
    atomicAdd(rs_raw + i_p0, rs0);
    atomicAdd(rs_raw + i_p1, rs1);
  }
}

extern "C" void kernel_launch(void* const* d_in, const int* in_sizes, int n_in,
                              void* d_out, int out_size, void* d_ws, size_t ws_size,
                              hipStream_t stream)
{
  (void)in_sizes; (void)n_in; (void)out_size; (void)ws_size;
  const float* x   = (const float*)d_in[0];
  const int*   adj = (const int*)d_in[1];
  const float* W   = (const float*)d_in[2];
  const float* a   = (const float*)d_in[3];
  float* out = (float*)d_out;

  char* ws = (char*)d_ws;
  // layout: hT (128MiB) | p (128MiB) | icn (32KiB) | irs (32KiB)
  // transient overlays:
  //   pre-scores : xb @ p+0 (8MiB), Wb @ p+8MiB (8MiB)   (dead once scores writes p)
  //   post-scores: Axb @ hT+0 (8MiB), xT @ hT+8MiB, Wb2 @ hT+16MiB (hT dead after scores)
  //   split-K partials (8 x 16MiB fp32) live in d_out, dead once reduce_cvt ran
  unsigned short* hT = (unsigned short*)ws;
  unsigned short* p  = (unsigned short*)(ws + 134217728ull);
  unsigned short* xb = p;
  unsigned short* Wb = p + (size_t)NN * KIN;           // 4M elems = 8MiB
  unsigned short* Axb = hT;
  unsigned short* xT  = hT + (size_t)NN * KIN;         // +8MiB
  unsigned short* Wb2 = hT + 2 * (size_t)NN * KIN;     // +16MiB
  float* icn = (float*)(ws + 268435456ull);
  float* irs = (float*)(ws + 268435456ull + 32768ull);
  float* parts = out;   // 128MiB of partials, overwritten later by final out

  // irs doubles as the raw row-sum accumulator for scores' atomics
  hipMemsetAsync(irs, 0, NN * sizeof(float), stream);

  const int n4 = NN * KIN / 4;
  cvt_f32_bf16<<<n4 / 256, 256, 0, stream>>>(x, xb, n4);
  cvt_f32_bf16<<<n4 / 256, 256, 0, stream>>>(W, Wb, n4);

  // hT[j,i] = sum_k W[j,k] x[i,k]  (NT: A=W rows j, B=x rows i)
  gemm_bt<1, 1><<<4096, 256, 0, stream>>>(Wb, xb, hT, nullptr, NN, NN, KIN);

  // icn[j] = 1 / ||hT[j,:]|| = 1 / col_norm(h)[j]
  row_reduce<0><<<NN, 256, 0, stream>>>(hT, icn, NN);

  // p[i,j] = adj ? exp(lrelu(...)) : 0 ; rowsums -> irs (raw). destroys xb, Wb
  scores_kernel<<<dim3(128, 16), 256, 0, stream>>>(hT, adj, a, icn, p, irs, NN / 16);

  // irs[i] = 1 / rowsum[i]
  invert_vec<<<NN / 256, 256, 0, stream>>>(irs);

  // rebuild bf16 W and transposed x in hT's (now dead) region
  cvt_f32_bf16<<<n4 / 256, 256, 0, stream>>>(W, Wb2, n4);
  transpose_cvt<<<dim3(NN / 64, KIN / 64), 256, 0, stream>>>(x, xT, NN, KIN);

  // Ax[i,c] = sum_j p[i,j] * x[j,c]  == NT(A=p, B=xT), K=8192 split 8 ways
  gemm_bt<2, 8><<<2048, 256, 0, stream>>>(p, xT, parts, nullptr, NN, KIN, NN);

  // Axb = bf16(sum of 8 partial planes)
  reduce_cvt<<<n4 / 256, 256, 0, stream>>>(parts, Axb, n4);

  // out[i,j] = (sum_c Ax[i,c] * W[j,c]) * irs[i]  == NT(A=Axb, B=Wb2), K=512
  gemm_bt<0, 1><<<4096, 256, 0, stream>>>(Axb, Wb2, out, irs, NN, NN, KIN);
}

// Round 9
// 525.284 us; speedup vs baseline: 1.8784x; 1.0356x over previous
//
#include <hip/hip_runtime.h>
#include <hip/hip_bf16.h>
#include <stdint.h>

#define NN 8192   // nodes == OUT
#define KIN 512   // input features

typedef __attribute__((ext_vector_type(8))) short bfx8;   // 8 bf16 (4 VGPRs) MFMA operand
typedef __attribute__((ext_vector_type(4))) float f32x4;  // MFMA accumulator
typedef __attribute__((ext_vector_type(4))) short sh4;

__device__ __forceinline__ float b2f(unsigned short u) {
  union { unsigned int i; float f; } z; z.i = ((unsigned int)u) << 16; return z.f;
}
__device__ __forceinline__ unsigned short f2b(float f) {
  __hip_bfloat16 h = __float2bfloat16(f);
  union { __hip_bfloat16 h; unsigned short u; } z; z.h = h; return z.u;
}

// async global->LDS, 16B per lane. LDS dest: wave-uniform base + lane*16.
__device__ __forceinline__ void async16(void* lds, const void* g) {
  __builtin_amdgcn_global_load_lds(
      (const __attribute__((address_space(1))) unsigned int*)g,
      (__attribute__((address_space(3))) unsigned int*)lds,
      16, 0, 0);
}

// fp32 -> bf16 convert (RNE), 4 elems/thread
__global__ __launch_bounds__(256)
void cvt_f32_bf16(const float* __restrict__ in, unsigned short* __restrict__ out, int n4) {
  int i = blockIdx.x * 256 + threadIdx.x;
  if (i >= n4) return;
  const float4 v = reinterpret_cast<const float4*>(in)[i];
  sh4 o;
  o.x = (short)f2b(v.x); o.y = (short)f2b(v.y);
  o.z = (short)f2b(v.z); o.w = (short)f2b(v.w);
  reinterpret_cast<sh4*>(out)[i] = o;
}

// sum 8 bf16 partial planes (fp32 accum) -> bf16. n8 = elems/8.
__global__ __launch_bounds__(256)
void reduce_cvt(const unsigned short* __restrict__ P, unsigned short* __restrict__ out, int n8) {
  const int i = blockIdx.x * 256 + threadIdx.x;
  if (i >= n8) return;
  const size_t plane = (size_t)NN * KIN / 8;   // in bfx8 units
  const bfx8* P8 = reinterpret_cast<const bfx8*>(P);
  bfx8 v = P8[i];
  float s[8];
#pragma unroll
  for (int j = 0; j < 8; ++j) s[j] = b2f((unsigned short)v[j]);
#pragma unroll
  for (int sp = 1; sp < 8; ++sp) {
    const bfx8 w = P8[i + sp * plane];
#pragma unroll
    for (int j = 0; j < 8; ++j) s[j] += b2f((unsigned short)w[j]);
  }
  bfx8 o;
#pragma unroll
  for (int j = 0; j < 8; ++j) o[j] = (short)f2b(s[j]);
  reinterpret_cast<bfx8*>(out)[i] = o;
}

// x (NR x NC f32) -> xT (NC x NR bf16)  AND  xb (NR x NC bf16)  (single x read)
__global__ __launch_bounds__(256)
void transpose_cvt(const float* __restrict__ x, unsigned short* __restrict__ xT,
                   unsigned short* __restrict__ xb, int NR, int NC) {
  __shared__ float t[64][65];
  const int i0 = blockIdx.x << 6;  // row block in x
  const int c0 = blockIdx.y << 6;  // col block in x
  const int tid = threadIdx.x;
  const int rl = tid >> 4;          // 0..15
  const int cl = (tid & 15) << 2;   // 0..60 step 4
#pragma unroll
  for (int ps = 0; ps < 4; ++ps) {
    const int r = rl + (ps << 4);
    const float4 v = *reinterpret_cast<const float4*>(&x[(size_t)(i0 + r) * NC + c0 + cl]);
    t[r][cl] = v.x; t[r][cl + 1] = v.y; t[r][cl + 2] = v.z; t[r][cl + 3] = v.w;
    sh4 o;
    o.x = (short)f2b(v.x); o.y = (short)f2b(v.y);
    o.z = (short)f2b(v.z); o.w = (short)f2b(v.w);
    *reinterpret_cast<sh4*>(&xb[(size_t)(i0 + r) * NC + c0 + cl]) = o;
  }
  __syncthreads();
  const int cr = tid >> 3;          // 0..31
  const int il = (tid & 7) << 3;    // 0..56 step 8
#pragma unroll
  for (int ps = 0; ps < 2; ++ps) {
    const int c = cr + (ps << 5);
    bfx8 o;
#pragma unroll
    for (int j = 0; j < 8; ++j) o[j] = (short)f2b(t[il + j][c]);
    *reinterpret_cast<bfx8*>(&xT[(size_t)(c0 + c) * NR + i0 + il]) = o;
  }
}

// NT GEMM: C[M x Nc] = A[M x K] * B[Nc x K]^T   (both row-major, K contiguous)
// 128x128 tile, BK=32, 4 waves (2x2 of 64x64), 16x16x32 bf16 MFMA.
// MODE 0: C fp32, scaled by rowscale[row], nontemporal (out: never re-read).
// MODE 1: C bf16, nontemporal (hT: re-read only by later kernels).
// MODE 2: C bf16 partial plane at C + split*M*Nc (split-K; temporal stores,
//         re-read immediately by reduce_cvt so L3 residency is valuable).
template<int MODE, int SPLITS>
__global__ __launch_bounds__(256)
void gemm_bt(const unsigned short* __restrict__ A,
             const unsigned short* __restrict__ B,
             void* __restrict__ C,
             const float* __restrict__ rowscale,
             int M, int Nc, int K)
{
  __shared__ unsigned short As[2][128 * 32];
  __shared__ unsigned short Bs[2][128 * 32];

  const int tid  = threadIdx.x;
  const int lane = tid & 63;
  const int wave = tid >> 6;
  const int wr   = wave >> 1, wc = wave & 1;

  // XCD-aware bijective swizzle (gridDim.x % 8 == 0 in all uses here)
  const int nwg = gridDim.x;
  const int cpx = nwg >> 3;
  const int bid = blockIdx.x;
  const int swz = (bid & 7) * cpx + (bid >> 3);
  const int bps = nwg / SPLITS;     // blocks per split
  const int split = swz / bps;
  const int rem   = swz % bps;
  const int nbn = Nc >> 7;
  const int bm  = (rem / nbn) << 7;
  const int bn  = (rem % nbn) << 7;
  const int klen  = K / SPLITS;
  const int kbase = split * klen;

  const int off0 = (wave << 10) + (lane << 4);
  const int r0   = off0 >> 6;
  const int k0e  = (off0 & 63) >> 1;
  const int r1   = r0 + 64;

  const unsigned short* Ag0 = A + (size_t)(bm + r0) * K + kbase + k0e;
  const unsigned short* Ag1 = A + (size_t)(bm + r1) * K + kbase + k0e;
  const unsigned short* Bg0 = B + (size_t)(bn + r0) * K + kbase + k0e;
  const unsigned short* Bg1 = B + (size_t)(bn + r1) * K + kbase + k0e;

  f32x4 acc[4][4];
#pragma unroll
  for (int m = 0; m < 4; ++m)
#pragma unroll
    for (int n = 0; n < 4; ++n)
      acc[m][n] = (f32x4){0.f, 0.f, 0.f, 0.f};

  const int ldsoff = (wave << 10);

  auto stage = [&](int buf, int kk) {
    char* la = (char*)&As[buf][0] + ldsoff;
    char* lb = (char*)&Bs[buf][0] + ldsoff;
    async16(la,        Ag0 + kk);
    async16(la + 4096, Ag1 + kk);
    async16(lb,        Bg0 + kk);
    async16(lb + 4096, Bg1 + kk);
  };

  stage(0, 0);
  __syncthreads();

  const int nk   = klen >> 5;
  const int arow = (wr << 6) + (lane & 15);
  const int brow = (wc << 6) + (lane & 15);
  const int koff = (lane >> 4) << 3;

  for (int kt = 0; kt < nk; ++kt) {
    const int cur = kt & 1;
    if (kt + 1 < nk) stage(cur ^ 1, (kt + 1) << 5);

    bfx8 af[4], bf[4];
#pragma unroll
    for (int m = 0; m < 4; ++m)
      af[m] = *reinterpret_cast<const bfx8*>(&As[cur][(arow + (m << 4)) * 32 + koff]);
#pragma unroll
    for (int n = 0; n < 4; ++n)
      bf[n] = *reinterpret_cast<const bfx8*>(&Bs[cur][(brow + (n << 4)) * 32 + koff]);

#pragma unroll
    for (int m = 0; m < 4; ++m)
#pragma unroll
      for (int n = 0; n < 4; ++n)
        acc[m][n] = __builtin_amdgcn_mfma_f32_16x16x32_bf16(af[m], bf[n], acc[m][n], 0, 0, 0);

    __syncthreads();  // drains vmcnt: next buffer staged; also guards buffer reuse
  }

  // C/D layout: col = lane&15, row = (lane>>4)*4 + reg
#pragma unroll
  for (int m = 0; m < 4; ++m) {
    const int rowb = bm + (wr << 6) + (m << 4) + ((lane >> 4) << 2);
#pragma unroll
    for (int j = 0; j < 4; ++j) {
      const int r = rowb + j;
      if (MODE == 1) {
        unsigned short* Cb = (unsigned short*)C;
#pragma unroll
        for (int n = 0; n < 4; ++n)
          __builtin_nontemporal_store(f2b(acc[m][n][j]),
              &Cb[(size_t)r * Nc + bn + (wc << 6) + (n << 4) + (lane & 15)]);
      } else if (MODE == 0) {
        const float s = rowscale[r];
        float* Cf = (float*)C;
#pragma unroll
        for (int n = 0; n < 4; ++n)
          __builtin_nontemporal_store(acc[m][n][j] * s,
              &Cf[(size_t)r * Nc + bn + (wc << 6) + (n << 4) + (lane & 15)]);
      } else {
        unsigned short* Cb = (unsigned short*)C + (size_t)split * M * Nc;
#pragma unroll
        for (int n = 0; n < 4; ++n)
          Cb[(size_t)r * Nc + bn + (wc << 6) + (n << 4) + (lane & 15)] = f2b(acc[m][n][j]);
      }
    }
  }
}

// row-wise reduce over bf16 matrix. MODE 0: 1/sqrt(sum x^2)  MODE 1: 1/sum
template<int MODE>
__global__ __launch_bounds__(256)
void row_reduce(const unsigned short* __restrict__ X, float* __restrict__ out, int ncols) {
  const int row = blockIdx.x;
  const unsigned short* xr = X + (size_t)row * ncols;
  float s = 0.f;
  for (int c = threadIdx.x * 8; c < ncols; c += 2048) {
    bfx8 v = *reinterpret_cast<const bfx8*>(xr + c);
#pragma unroll
    for (int j = 0; j < 8; ++j) {
      float f = b2f((unsigned short)v[j]);
      s += (MODE == 0) ? f * f : f;
    }
  }
#pragma unroll
  for (int o = 32; o > 0; o >>= 1) s += __shfl_down(s, o);
  __shared__ float red[4];
  if ((threadIdx.x & 63) == 0) red[threadIdx.x >> 6] = s;
  __syncthreads();
  if (threadIdx.x == 0) {
    float t = red[0] + red[1] + red[2] + red[3];
    out[row] = (MODE == 0) ? (1.0f / sqrtf(t)) : (1.0f / t);
  }
}

// in-place 1/x over a small float vector
__global__ __launch_bounds__(256)
void invert_vec(float* __restrict__ v) {
  const int i = blockIdx.x * 256 + threadIdx.x;
  v[i] = 1.0f / v[i];
}

// p[i,j] = adj[i,j] ? exp(lrelu(hT[j,i]*a1[i]*icn[j] + hT[i,j]*a2[j]*icn[i])) : 0
// Vectorized: 8 j per thread. Also accumulates row sums of p into rs_raw[i].
__global__ __launch_bounds__(256)
void scores_kernel(const unsigned short* __restrict__ hT,
                   const int* __restrict__ adj,
                   const float* __restrict__ a,
                   const float* __restrict__ icn,
                   unsigned short* __restrict__ p,
                   float* __restrict__ rs_raw,
                   int strip)
{
  __shared__ unsigned short T1t[64][72];

  const int tid   = threadIdx.x;
  const int i0    = blockIdx.x << 6;
  const int jbase = blockIdx.y * strip;
  const int ntile = strip >> 6;

  const int slot = tid & 7;
  const int jb   = slot << 3;
  const int il0  = tid >> 3;
  const int i_p0 = i0 + il0;
  const int i_p1 = i_p0 + 32;
  const float a1_0 = a[i_p0], ici_0 = icn[i_p0];
  const float a1_1 = a[i_p1], ici_1 = icn[i_p1];
  float rs0 = 0.f, rs1 = 0.f;

  const int rblk0 = (((jb >> 3) ^ ((il0 >> 3) & 7)) << 3);
  const int rblk1 = (((jb >> 3) ^ (((il0 + 32) >> 3) & 7)) << 3);

  for (int jt = 0; jt < ntile; ++jt) {
    const int j0 = jbase + (jt << 6);
    __syncthreads();
#pragma unroll
    for (int ss = 0; ss < 2; ++ss) {
      const int u  = tid + (ss << 8);
      const int jr = u >> 3;
      const int cb = (u & 7) << 3;
      const bfx8 v = *reinterpret_cast<const bfx8*>(hT + (size_t)(j0 + jr) * NN + i0 + cb);
      const int colp = ((((jr >> 3) ^ (u & 7)) << 3) | (jr & 7));
#pragma unroll
      for (int k = 0; k < 8; ++k) T1t[cb + k][colp] = (unsigned short)v[k];
    }
    __syncthreads();

    const int j = j0 + jb;
    const float4 ic0 = *reinterpret_cast<const float4*>(icn + j);
    const float4 ic1 = *reinterpret_cast<const float4*>(icn + j + 4);
    const float4 a20 = *reinterpret_cast<const float4*>(a + NN + j);
    const float4 a21 = *reinterpret_cast<const float4*>(a + NN + j + 4);
    const float icj[8] = {ic0.x, ic0.y, ic0.z, ic0.w, ic1.x, ic1.y, ic1.z, ic1.w};
    const float a2j[8] = {a20.x, a20.y, a20.z, a20.w, a21.x, a21.y, a21.z, a21.w};

#pragma unroll
    for (int ps = 0; ps < 2; ++ps) {
      const int il   = (ps == 0) ? il0 : il0 + 32;
      const int i    = (ps == 0) ? i_p0 : i_p1;
      const float a1 = (ps == 0) ? a1_0 : a1_1;
      const float ii = (ps == 0) ? ici_0 : ici_1;
      const int rb   = (ps == 0) ? rblk0 : rblk1;

      const bfx8 hijv = *reinterpret_cast<const bfx8*>(&T1t[il][rb]);
      const bfx8 hjiv = *reinterpret_cast<const bfx8*>(hT + (size_t)i * NN + j);
      const int4 ad0  = *reinterpret_cast<const int4*>(adj + (size_t)i * NN + j);
      const int4 ad1  = *reinterpret_cast<const int4*>(adj + (size_t)i * NN + j + 4);
      const int adv[8] = {ad0.x, ad0.y, ad0.z, ad0.w, ad1.x, ad1.y, ad1.z, ad1.w};

      bfx8 o;
      float rs = 0.f;
#pragma unroll
      for (int k = 0; k < 8; ++k) {
        const float hij = b2f((unsigned short)hijv[k]);
        const float hji = b2f((unsigned short)hjiv[k]);
        const float e0  = hij * (a1 * icj[k]) + hji * (a2j[k] * ii);
        const float e   = e0 > 0.f ? e0 : 0.2f * e0;
        const float pv  = (adv[k] > 0) ? __expf(e) : 0.f;
        const unsigned short ub = f2b(pv);
        o[k] = (short)ub;
        rs += b2f(ub);   // accumulate the rounded value (matches reading back bf16 p)
      }
      *reinterpret_cast<bfx8*>(p + (size_t)i * NN + j) = o;
      if (ps == 0) rs0 += rs; else rs1 += rs;
    }
  }

  // reduce across the 8 j-slot lanes (lane groups are 8-aligned)
#pragma unroll
  for (int o = 1; o < 8; o <<= 1) {
    rs0 += __shfl_xor(rs0, o);
    rs1 += __shfl_xor(rs1, o);
  }
  if (slot == 0) {
    atomicAdd(rs_raw + i_p0, rs0);
    atomicAdd(rs_raw + i_p1, rs1);
  }
}

extern "C" void kernel_launch(void* const* d_in, const int* in_sizes, int n_in,
                              void* d_out, int out_size, void* d_ws, size_t ws_size,
                              hipStream_t stream)
{
  (void)in_sizes; (void)n_in; (void)out_size; (void)ws_size;
  const float* x   = (const float*)d_in[0];
  const int*   adj = (const int*)d_in[1];
  const float* W   = (const float*)d_in[2];
  const float* a   = (const float*)d_in[3];
  float* out = (float*)d_out;

  char* ws = (char*)d_ws;
  // layout (no recycling; ~288 MiB used, ws ~1 GiB per poison fill):
  //   hT 128MiB | p 128MiB | icn 32KiB | irs 32KiB | xb 8MiB | Wb 8MiB | xT 8MiB | Axb 8MiB
  // split-K bf16 partials (8 x 8MiB) live in d_out, dead before gemm2b writes it.
  unsigned short* hT = (unsigned short*)ws;
  unsigned short* p  = (unsigned short*)(ws + 134217728ull);
  float* icn = (float*)(ws + 268435456ull);
  float* irs = (float*)(ws + 268435456ull + 32768ull);
  unsigned short* xb  = (unsigned short*)(ws + 268435456ull + 65536ull);
  unsigned short* Wb  = xb + (size_t)NN * KIN;
  unsigned short* xT  = Wb + (size_t)NN * KIN;
  unsigned short* Axb = xT + (size_t)NN * KIN;
  unsigned short* parts = (unsigned short*)out;   // 64MiB bf16, overwritten later

  // irs doubles as the raw row-sum accumulator for scores' atomics
  hipMemsetAsync(irs, 0, NN * sizeof(float), stream);

  const int n4 = NN * KIN / 4;
  // xb + xT from a single read of x
  transpose_cvt<<<dim3(NN / 64, KIN / 64), 256, 0, stream>>>(x, xT, xb, NN, KIN);
  cvt_f32_bf16<<<n4 / 256, 256, 0, stream>>>(W, Wb, n4);

  // hT[j,i] = sum_k W[j,k] x[i,k]  (NT: A=W rows j, B=x rows i)
  gemm_bt<1, 1><<<4096, 256, 0, stream>>>(Wb, xb, hT, nullptr, NN, NN, KIN);

  // icn[j] = 1 / ||hT[j,:]|| = 1 / col_norm(h)[j]
  row_reduce<0><<<NN, 256, 0, stream>>>(hT, icn, NN);

  // p[i,j] = adj ? exp(lrelu(...)) : 0 ; rowsums -> irs (raw)
  scores_kernel<<<dim3(128, 16), 256, 0, stream>>>(hT, adj, a, icn, p, irs, NN / 16);

  // irs[i] = 1 / rowsum[i]
  invert_vec<<<NN / 256, 256, 0, stream>>>(irs);

  // Ax[i,c] = sum_j p[i,j] * x[j,c]  (split-K 8, bf16 partials in d_out)
  gemm_bt<2, 8><<<2048, 256, 0, stream>>>(p, xT, parts, nullptr, NN, KIN, NN);

  // Axb = bf16(sum of 8 bf16 partial planes)
  reduce_cvt<<<NN * KIN / 8 / 256, 256, 0, stream>>>(parts, Axb, NN * KIN / 8);

  // out[i,j] = (sum_c Ax[i,c] * W[j,c]) * irs[i]  (K=512)
  gemm_bt<0, 1><<<4096, 256, 0, stream>>>(Axb, Wb, out, irs, NN, NN, KIN);
}

// Round 10
// 495.237 us; speedup vs baseline: 1.9923x; 1.0607x over previous
//
#include <hip/hip_runtime.h>
#include <hip/hip_bf16.h>
#include <stdint.h>

#define NN 8192   // nodes == OUT
#define KIN 512   // input features

typedef __attribute__((ext_vector_type(8))) short bfx8;   // 8 bf16 (4 VGPRs) MFMA operand
typedef __attribute__((ext_vector_type(4))) float f32x4;  // MFMA accumulator
typedef __attribute__((ext_vector_type(4))) short sh4;

__device__ __forceinline__ float b2f(unsigned short u) {
  union { unsigned int i; float f; } z; z.i = ((unsigned int)u) << 16; return z.f;
}
__device__ __forceinline__ unsigned short f2b(float f) {
  __hip_bfloat16 h = __float2bfloat16(f);
  union { __hip_bfloat16 h; unsigned short u; } z; z.h = h; return z.u;
}

// async global->LDS, 16B per lane. LDS dest: wave-uniform base + lane*16.
__device__ __forceinline__ void async16(void* lds, const void* g) {
  __builtin_amdgcn_global_load_lds(
      (const __attribute__((address_space(1))) unsigned int*)g,
      (__attribute__((address_space(3))) unsigned int*)lds,
      16, 0, 0);
}

// fp32 -> bf16 convert (RNE), 4 elems/thread
__global__ __launch_bounds__(256)
void cvt_f32_bf16(const float* __restrict__ in, unsigned short* __restrict__ out, int n4) {
  int i = blockIdx.x * 256 + threadIdx.x;
  if (i >= n4) return;
  const float4 v = reinterpret_cast<const float4*>(in)[i];
  sh4 o;
  o.x = (short)f2b(v.x); o.y = (short)f2b(v.y);
  o.z = (short)f2b(v.z); o.w = (short)f2b(v.w);
  reinterpret_cast<sh4*>(out)[i] = o;
}

// sum 8 bf16 partial planes (fp32 accum) -> bf16. n8 = elems/8.
__global__ __launch_bounds__(256)
void reduce_cvt(const unsigned short* __restrict__ P, unsigned short* __restrict__ out, int n8) {
  const int i = blockIdx.x * 256 + threadIdx.x;
  if (i >= n8) return;
  const size_t plane = (size_t)NN * KIN / 8;   // in bfx8 units
  const bfx8* P8 = reinterpret_cast<const bfx8*>(P);
  bfx8 v = P8[i];
  float s[8];
#pragma unroll
  for (int j = 0; j < 8; ++j) s[j] = b2f((unsigned short)v[j]);
#pragma unroll
  for (int sp = 1; sp < 8; ++sp) {
    const bfx8 w = P8[i + sp * plane];
#pragma unroll
    for (int j = 0; j < 8; ++j) s[j] += b2f((unsigned short)w[j]);
  }
  bfx8 o;
#pragma unroll
  for (int j = 0; j < 8; ++j) o[j] = (short)f2b(s[j]);
  reinterpret_cast<bfx8*>(out)[i] = o;
}

// x (NR x NC f32) -> xT (NC x NR bf16)  AND  xb (NR x NC bf16)  (single x read)
__global__ __launch_bounds__(256)
void transpose_cvt(const float* __restrict__ x, unsigned short* __restrict__ xT,
                   unsigned short* __restrict__ xb, int NR, int NC) {
  __shared__ float t[64][65];
  const int i0 = blockIdx.x << 6;  // row block in x
  const int c0 = blockIdx.y << 6;  // col block in x
  const int tid = threadIdx.x;
  const int rl = tid >> 4;          // 0..15
  const int cl = (tid & 15) << 2;   // 0..60 step 4
#pragma unroll
  for (int ps = 0; ps < 4; ++ps) {
    const int r = rl + (ps << 4);
    const float4 v = *reinterpret_cast<const float4*>(&x[(size_t)(i0 + r) * NC + c0 + cl]);
    t[r][cl] = v.x; t[r][cl + 1] = v.y; t[r][cl + 2] = v.z; t[r][cl + 3] = v.w;
    sh4 o;
    o.x = (short)f2b(v.x); o.y = (short)f2b(v.y);
    o.z = (short)f2b(v.z); o.w = (short)f2b(v.w);
    *reinterpret_cast<sh4*>(&xb[(size_t)(i0 + r) * NC + c0 + cl]) = o;
  }
  __syncthreads();
  const int cr = tid >> 3;          // 0..31
  const int il = (tid & 7) << 3;    // 0..56 step 8
#pragma unroll
  for (int ps = 0; ps < 2; ++ps) {
    const int c = cr + (ps << 5);
    bfx8 o;
#pragma unroll
    for (int j = 0; j < 8; ++j) o[j] = (short)f2b(t[il + j][c]);
    *reinterpret_cast<bfx8*>(&xT[(size_t)(c0 + c) * NR + i0 + il]) = o;
  }
}

// NT GEMM: C[M x Nc] = A[M x K] * B[Nc x K]^T   (both row-major, K contiguous)
// 128x128 tile, BK=32, 4 waves (2x2 of 64x64), 16x16x32 bf16 MFMA.
// MODE 0: C fp32, scaled by rowscale[row], nontemporal (out: never re-read).
// MODE 1: C bf16, nontemporal (hT: re-read only by later kernels).
// MODE 2: C bf16 partial plane at C + split*M*Nc (split-K; temporal stores).
// L2T: 2D super-tile mapping per XCD chunk so each XCD's concurrent blocks
//      work on an 8x8 tile region (A-slice 1MiB + B-slice 1MiB fits 4MiB L2)
//      instead of an m-major sweep whose 8MiB B working set thrashes L2.
//      Requires SPLITS==1, M==Nc, nwg==4096 (chunk 512, 64x64 tile grid).
template<int MODE, int SPLITS, int L2T>
__global__ __launch_bounds__(256)
void gemm_bt(const unsigned short* __restrict__ A,
             const unsigned short* __restrict__ B,
             void* __restrict__ C,
             const float* __restrict__ rowscale,
             int M, int Nc, int K)
{
  __shared__ unsigned short As[2][128 * 32];
  __shared__ unsigned short Bs[2][128 * 32];

  const int tid  = threadIdx.x;
  const int lane = tid & 63;
  const int wave = tid >> 6;
  const int wr   = wave >> 1, wc = wave & 1;

  // XCD-aware bijective swizzle (gridDim.x % 8 == 0 in all uses here)
  const int nwg = gridDim.x;
  const int cpx = nwg >> 3;
  const int bid = blockIdx.x;
  const int swz = (bid & 7) * cpx + (bid >> 3);

  int split, bm, bn;
  if (L2T) {
    // bijective: (x, l) <-> (bm_idx, bn_idx); x = XCD chunk (512 blocks)
    split = 0;
    const int x = swz >> 9;
    const int l = swz & 511;
    const int s = l >> 6;        // super-tile column group
    const int w = l & 63;        // 8x8 within super-tile
    bm = (((x << 3) | (w >> 3))) << 7;
    bn = (((s << 3) | (w & 7))) << 7;
  } else {
    const int bps = nwg / SPLITS;     // blocks per split
    split = swz / bps;
    const int rem = swz % bps;
    const int nbn = Nc >> 7;
    bm = (rem / nbn) << 7;
    bn = (rem % nbn) << 7;
  }
  const int klen  = K / SPLITS;
  const int kbase = split * klen;

  const int off0 = (wave << 10) + (lane << 4);
  const int r0   = off0 >> 6;
  const int k0e  = (off0 & 63) >> 1;
  const int r1   = r0 + 64;

  const unsigned short* Ag0 = A + (size_t)(bm + r0) * K + kbase + k0e;
  const unsigned short* Ag1 = A + (size_t)(bm + r1) * K + kbase + k0e;
  const unsigned short* Bg0 = B + (size_t)(bn + r0) * K + kbase + k0e;
  const unsigned short* Bg1 = B + (size_t)(bn + r1) * K + kbase + k0e;

  f32x4 acc[4][4];
#pragma unroll
  for (int m = 0; m < 4; ++m)
#pragma unroll
    for (int n = 0; n < 4; ++n)
      acc[m][n] = (f32x4){0.f, 0.f, 0.f, 0.f};

  const int ldsoff = (wave << 10);

  auto stage = [&](int buf, int kk) {
    char* la = (char*)&As[buf][0] + ldsoff;
    char* lb = (char*)&Bs[buf][0] + ldsoff;
    async16(la,        Ag0 + kk);
    async16(la + 4096, Ag1 + kk);
    async16(lb,        Bg0 + kk);
    async16(lb + 4096, Bg1 + kk);
  };

  stage(0, 0);
  __syncthreads();

  const int nk   = klen >> 5;
  const int arow = (wr << 6) + (lane & 15);
  const int brow = (wc << 6) + (lane & 15);
  const int koff = (lane >> 4) << 3;

  for (int kt = 0; kt < nk; ++kt) {
    const int cur = kt & 1;
    if (kt + 1 < nk) stage(cur ^ 1, (kt + 1) << 5);

    bfx8 af[4], bf[4];
#pragma unroll
    for (int m = 0; m < 4; ++m)
      af[m] = *reinterpret_cast<const bfx8*>(&As[cur][(arow + (m << 4)) * 32 + koff]);
#pragma unroll
    for (int n = 0; n < 4; ++n)
      bf[n] = *reinterpret_cast<const bfx8*>(&Bs[cur][(brow + (n << 4)) * 32 + koff]);

#pragma unroll
    for (int m = 0; m < 4; ++m)
#pragma unroll
      for (int n = 0; n < 4; ++n)
        acc[m][n] = __builtin_amdgcn_mfma_f32_16x16x32_bf16(af[m], bf[n], acc[m][n], 0, 0, 0);

    __syncthreads();  // drains vmcnt: next buffer staged; also guards buffer reuse
  }

  // C/D layout: col = lane&15, row = (lane>>4)*4 + reg
#pragma unroll
  for (int m = 0; m < 4; ++m) {
    const int rowb = bm + (wr << 6) + (m << 4) + ((lane >> 4) << 2);
#pragma unroll
    for (int j = 0; j < 4; ++j) {
      const int r = rowb + j;
      if (MODE == 1) {
        unsigned short* Cb = (unsigned short*)C;
#pragma unroll
        for (int n = 0; n < 4; ++n)
          __builtin_nontemporal_store(f2b(acc[m][n][j]),
              &Cb[(size_t)r * Nc + bn + (wc << 6) + (n << 4) + (lane & 15)]);
      } else if (MODE == 0) {
        const float s = rowscale[r];
        float* Cf = (float*)C;
#pragma unroll
        for (int n = 0; n < 4; ++n)
          __builtin_nontemporal_store(acc[m][n][j] * s,
              &Cf[(size_t)r * Nc + bn + (wc << 6) + (n << 4) + (lane & 15)]);
      } else {
        unsigned short* Cb = (unsigned short*)C + (size_t)split * M * Nc;
#pragma unroll
        for (int n = 0; n < 4; ++n)
          Cb[(size_t)r * Nc + bn + (wc << 6) + (n << 4) + (lane & 15)] = f2b(acc[m][n][j]);
      }
    }
  }
}

// row-wise reduce over bf16 matrix. MODE 0: 1/sqrt(sum x^2)  MODE 1: 1/sum
template<int MODE>
__global__ __launch_bounds__(256)
void row_reduce(const unsigned short* __restrict__ X, float* __restrict__ out, int ncols) {
  const int row = blockIdx.x;
  const unsigned short* xr = X + (size_t)row * ncols;
  float s = 0.f;
  for (int c = threadIdx.x * 8; c < ncols; c += 2048) {
    bfx8 v = *reinterpret_cast<const bfx8*>(xr + c);
#pragma unroll
    for (int j = 0; j < 8; ++j) {
      float f = b2f((unsigned short)v[j]);
      s += (MODE == 0) ? f * f : f;
    }
  }
#pragma unroll
  for (int o = 32; o > 0; o >>= 1) s += __shfl_down(s, o);
  __shared__ float red[4];
  if ((threadIdx.x & 63) == 0) red[threadIdx.x >> 6] = s;
  __syncthreads();
  if (threadIdx.x == 0) {
    float t = red[0] + red[1] + red[2] + red[3];
    out[row] = (MODE == 0) ? (1.0f / sqrtf(t)) : (1.0f / t);
  }
}

// in-place 1/x over a small float vector
__global__ __launch_bounds__(256)
void invert_vec(float* __restrict__ v) {
  const int i = blockIdx.x * 256 + threadIdx.x;
  v[i] = 1.0f / v[i];
}

// p[i,j] = adj[i,j] ? exp(lrelu(hT[j,i]*a1[i]*icn[j] + hT[i,j]*a2[j]*icn[i])) : 0
// Vectorized: 8 j per thread. Also accumulates row sums of p into rs_raw[i].
__global__ __launch_bounds__(256)
void scores_kernel(const unsigned short* __restrict__ hT,
                   const int* __restrict__ adj,
                   const float* __restrict__ a,
                   const float* __restrict__ icn,
                   unsigned short* __restrict__ p,
                   float* __restrict__ rs_raw,
                   int strip)
{
  __shared__ unsigned short T1t[64][72];

  const int tid   = threadIdx.x;
  const int i0    = blockIdx.x << 6;
  const int jbase = blockIdx.y * strip;
  const int ntile = strip >> 6;

  const int slot = tid & 7;
  const int jb   = slot << 3;
  const int il0  = tid >> 3;
  const int i_p0 = i0 + il0;
  const int i_p1 = i_p0 + 32;
  const float a1_0 = a[i_p0], ici_0 = icn[i_p0];
  const float a1_1 = a[i_p1], ici_1 = icn[i_p1];
  float rs0 = 0.f, rs1 = 0.f;

  const int rblk0 = (((jb >> 3) ^ ((il0 >> 3) & 7)) << 3);
  const int rblk1 = (((jb >> 3) ^ (((il0 + 32) >> 3) & 7)) << 3);

  for (int jt = 0; jt < ntile; ++jt) {
    const int j0 = jbase + (jt << 6);
    __syncthreads();
#pragma unroll
    for (int ss = 0; ss < 2; ++ss) {
      const int u  = tid + (ss << 8);
      const int jr = u >> 3;
      const int cb = (u & 7) << 3;
      const bfx8 v = *reinterpret_cast<const bfx8*>(hT + (size_t)(j0 + jr) * NN + i0 + cb);
      const int colp = ((((jr >> 3) ^ (u & 7)) << 3) | (jr & 7));
#pragma unroll
      for (int k = 0; k < 8; ++k) T1t[cb + k][colp] = (unsigned short)v[k];
    }
    __syncthreads();

    const int j = j0 + jb;
    const float4 ic0 = *reinterpret_cast<const float4*>(icn + j);
    const float4 ic1 = *reinterpret_cast<const float4*>(icn + j + 4);
    const float4 a20 = *reinterpret_cast<const float4*>(a + NN + j);
    const float4 a21 = *reinterpret_cast<const float4*>(a + NN + j + 4);
    const float icj[8] = {ic0.x, ic0.y, ic0.z, ic0.w, ic1.x, ic1.y, ic1.z, ic1.w};
    const float a2j[8] = {a20.x, a20.y, a20.z, a20.w, a21.x, a21.y, a21.z, a21.w};

#pragma unroll
    for (int ps = 0; ps < 2; ++ps) {
      const int il   = (ps == 0) ? il0 : il0 + 32;
      const int i    = (ps == 0) ? i_p0 : i_p1;
      const float a1 = (ps == 0) ? a1_0 : a1_1;
      const float ii = (ps == 0) ? ici_0 : ici_1;
      const int rb   = (ps == 0) ? rblk0 : rblk1;

      const bfx8 hijv = *reinterpret_cast<const bfx8*>(&T1t[il][rb]);
      const bfx8 hjiv = *reinterpret_cast<const bfx8*>(hT + (size_t)i * NN + j);
      const int4 ad0  = *reinterpret_cast<const int4*>(adj + (size_t)i * NN + j);
      const int4 ad1  = *reinterpret_cast<const int4*>(adj + (size_t)i * NN + j + 4);
      const int adv[8] = {ad0.x, ad0.y, ad0.z, ad0.w, ad1.x, ad1.y, ad1.z, ad1.w};

      bfx8 o;
      float rs = 0.f;
#pragma unroll
      for (int k = 0; k < 8; ++k) {
        const float hij = b2f((unsigned short)hijv[k]);
        const float hji = b2f((unsigned short)hjiv[k]);
        const float e0  = hij * (a1 * icj[k]) + hji * (a2j[k] * ii);
        const float e   = e0 > 0.f ? e0 : 0.2f * e0;
        const float pv  = (adv[k] > 0) ? __expf(e) : 0.f;
        const unsigned short ub = f2b(pv);
        o[k] = (short)ub;
        rs += b2f(ub);   // accumulate the rounded value (matches reading back bf16 p)
      }
      *reinterpret_cast<bfx8*>(p + (size_t)i * NN + j) = o;
      if (ps == 0) rs0 += rs; else rs1 += rs;
    }
  }

  // reduce across the 8 j-slot lanes (lane groups are 8-aligned)
#pragma unroll
  for (int o = 1; o < 8; o <<= 1) {
    rs0 += __shfl_xor(rs0, o);
    rs1 += __shfl_xor(rs1, o);
  }
  if (slot == 0) {
    atomicAdd(rs_raw + i_p0, rs0);
    atomicAdd(rs_raw + i_p1, rs1);
  }
}

extern "C" void kernel_launch(void* const* d_in, const int* in_sizes, int n_in,
                              void* d_out, int out_size, void* d_ws, size_t ws_size,
                              hipStream_t stream)
{
  (void)in_sizes; (void)n_in; (void)out_size; (void)ws_size;
  const float* x   = (const float*)d_in[0];
  const int*   adj = (const int*)d_in[1];
  const float* W   = (const float*)d_in[2];
  const float* a   = (const float*)d_in[3];
  float* out = (float*)d_out;

  char* ws = (char*)d_ws;
  // layout (no recycling; ~288 MiB used, ws ~1 GiB per poison fill):
  //   hT 128MiB | p 128MiB | icn 32KiB | irs 32KiB | xb 8MiB | Wb 8MiB | xT 8MiB | Axb 8MiB
  // split-K bf16 partials (8 x 8MiB) live in d_out, dead before gemm2b writes it.
  unsigned short* hT = (unsigned short*)ws;
  unsigned short* p  = (unsigned short*)(ws + 134217728ull);
  float* icn = (float*)(ws + 268435456ull);
  float* irs = (float*)(ws + 268435456ull + 32768ull);
  unsigned short* xb  = (unsigned short*)(ws + 268435456ull + 65536ull);
  unsigned short* Wb  = xb + (size_t)NN * KIN;
  unsigned short* xT  = Wb + (size_t)NN * KIN;
  unsigned short* Axb = xT + (size_t)NN * KIN;
  unsigned short* parts = (unsigned short*)out;   // 64MiB bf16, overwritten later

  // irs doubles as the raw row-sum accumulator for scores' atomics
  hipMemsetAsync(irs, 0, NN * sizeof(float), stream);

  const int n4 = NN * KIN / 4;
  // xb + xT from a single read of x
  transpose_cvt<<<dim3(NN / 64, KIN / 64), 256, 0, stream>>>(x, xT, xb, NN, KIN);
  cvt_f32_bf16<<<n4 / 256, 256, 0, stream>>>(W, Wb, n4);

  // hT[j,i] = sum_k W[j,k] x[i,k]  (NT: A=W rows j, B=x rows i)
  gemm_bt<1, 1, 1><<<4096, 256, 0, stream>>>(Wb, xb, hT, nullptr, NN, NN, KIN);

  // icn[j] = 1 / ||hT[j,:]|| = 1 / col_norm(h)[j]
  row_reduce<0><<<NN, 256, 0, stream>>>(hT, icn, NN);

  // p[i,j] = adj ? exp(lrelu(...)) : 0 ; rowsums -> irs (raw)
  scores_kernel<<<dim3(128, 16), 256, 0, stream>>>(hT, adj, a, icn, p, irs, NN / 16);

  // irs[i] = 1 / rowsum[i]
  invert_vec<<<NN / 256, 256, 0, stream>>>(irs);

  // Ax[i,c] = sum_j p[i,j] * x[j,c]  (split-K 8, bf16 partials in d_out)
  gemm_bt<2, 8, 0><<<2048, 256, 0, stream>>>(p, xT, parts, nullptr, NN, KIN, NN);

  // Axb = bf16(sum of 8 bf16 partial planes)
  reduce_cvt<<<NN * KIN / 8 / 256, 256, 0, stream>>>(parts, Axb, NN * KIN / 8);

  // out[i,j] = (sum_c Ax[i,c] * W[j,c]) * irs[i]  (K=512)
  gemm_bt<0, 1, 1><<<4096, 256, 0, stream>>>(Axb, Wb, out, irs, NN, NN, KIN);
}